// Round 8
// baseline (88.781 us; speedup 1.0000x reference)
//
#include <hip/hip_runtime.h>
#include <math.h>

#define BB 128
#define OUTROW 1259   // 2+1+256+1000

typedef float vf4 __attribute__((ext_vector_type(4)));

// A(t) = sin(H*pi*r)*cos(pi*r)/(H*sin(pi*r)),  B(t) = sin(H*pi*r)/H,  r = t - round(t)
__device__ __forceinline__ void dirichlet_ab(float t, float& A, float& Bv) {
    float r = t - rintf(t);
    float s256 = sinpif(256.0f * r);
    Bv = s256 * (1.0f / 256.0f);
    if (fabsf(r) < 1e-6f) {
        A = 1.0f;
    } else {
        float sp = sinpif(r), cp = cospif(r);
        A = Bv * cp / sp;
    }
}

// One block per (b, c). 256 threads = 4 waves; wave w owns iy = {2w, 2w+1}.
// Non-temporal image loads: 96MB single-use stream.
__global__ __launch_bounds__(256) void interp_kernel(
    const float* __restrict__ image, const float* __restrict__ loc,
    const float* __restrict__ scl, float* __restrict__ pix)
{
    __shared__ float U[256 * 16];
    __shared__ float V[16 * 260];
    __shared__ float T[16 * 260];

    int bid = blockIdx.x;
    int b = bid / 3, c = bid % 3;
    int tid = threadIdx.x;
    float l0 = loc[2 * b], l1 = loc[2 * b + 1], sc = scl[b];

    {
        int p = tid;
        float tp = (float)p * (1.0f / 256.0f);
        #pragma unroll
        for (int iy = 0; iy < 8; ++iy) {
            float A, Bv;
            float y = ((float)iy * 0.125f - l0) * sc;
            dirichlet_ab(y - tp, A, Bv);
            int w = iy >> 1, o = iy & 1;
            U[p * 16 + w * 4 + o] = A;
            U[p * 16 + w * 4 + 2 + o] = Bv;
            float x = ((float)iy * 0.125f - l1) * sc;
            dirichlet_ab(x - tp, A, Bv);
            V[iy * 260 + p] = A;
            V[(8 + iy) * 260 + p] = Bv;
        }
    }
    __syncthreads();

    int wave = tid >> 6, lane = tid & 63;
    const float* img = image + (size_t)(b * 3 + c) * 65536 + lane * 4;

    float aA0[4] = {0, 0, 0, 0}, aA1[4] = {0, 0, 0, 0};
    float aB0[4] = {0, 0, 0, 0}, aB1[4] = {0, 0, 0, 0};
    #pragma unroll 4
    for (int p = 0; p < 256; ++p) {
        vf4 v = __builtin_nontemporal_load((const vf4*)(img + p * 256));
        const float4 u = *(const float4*)(&U[p * 16 + wave * 4]);
        aA0[0] += u.x * v[0]; aA0[1] += u.x * v[1]; aA0[2] += u.x * v[2]; aA0[3] += u.x * v[3];
        aA1[0] += u.y * v[0]; aA1[1] += u.y * v[1]; aA1[2] += u.y * v[2]; aA1[3] += u.y * v[3];
        aB0[0] += u.z * v[0]; aB0[1] += u.z * v[1]; aB0[2] += u.z * v[2]; aB0[3] += u.z * v[3];
        aB1[0] += u.w * v[0]; aB1[1] += u.w * v[1]; aB1[2] += u.w * v[2]; aB1[3] += u.w * v[3];
    }
    int iy0 = wave * 2;
    int q0 = lane * 4;
    #pragma unroll
    for (int j = 0; j < 4; ++j) {
        T[iy0 * 260 + q0 + j]       = aA0[j];
        T[(iy0 + 1) * 260 + q0 + j] = aA1[j];
        T[(8 + iy0) * 260 + q0 + j]     = aB0[j];
        T[(8 + iy0 + 1) * 260 + q0 + j] = aB1[j];
    }
    __syncthreads();

    int n = tid >> 2, sub = tid & 3;
    int iy = n >> 3, ix = n & 7;
    float s = 0.f;
    #pragma unroll 8
    for (int i = 0; i < 64; ++i) {
        int q = sub + 4 * i;
        s += T[iy * 260 + q] * V[ix * 260 + q] - T[(8 + iy) * 260 + q] * V[(8 + ix) * 260 + q];
    }
    s += __shfl_xor(s, 1);
    s += __shfl_xor(s, 2);
    if (sub == 0) pix[(b * 64 + n) * 3 + c] = s;
}

// L2 warm for the MAIN-CHAIN weights (2.3 MB), AFTER interp's 96MB stream.
// 256 blocks: slice = bid>>3 (32 slices), 8 readers per slice spread across
// XCDs (bid&7 ~ XCD round-robin) so every XCD L2 gets every line.
__device__ __forceinline__ void warm_range(const float* __restrict__ p, int n4,
                                           int slice, int tid, float& s) {
    int per = (n4 + 31) / 32;
    int lo = slice * per;
    int hi = lo + per; if (hi > n4) hi = n4;
    for (int i = lo + tid; i < hi; i += 256) {
        const float4 v = *(const float4*)(p + 4 * (size_t)i);
        s += v.x + v.y + v.z + v.w;
    }
}

__global__ __launch_bounds__(256) void warm_l2(
    const float* __restrict__ w0, const float* __restrict__ rw,
    const float* __restrict__ wf, const float* __restrict__ cw0,
    const float* __restrict__ crw, float* __restrict__ sink)
{
    int slice = (int)(blockIdx.x >> 3);   // 0..31
    int tid = threadIdx.x;
    float s = 0.f;
    warm_range(w0,  28864, slice, tid, s);   // 451*256/4
    warm_range(rw,  65536, slice, tid, s);   // 4*256*256/4
    warm_range(wf,  16576, slice, tid, s);   // 256*259/4
    warm_range(cw0, 16384, slice, tid, s);
    warm_range(crw, 16384, slice, tid, s);
    if (s == 1.0e30f) sink[0] = s;           // keep loads live, never taken
}

// 256x256 GEMV piece: all 16 float4 weight loads issued first, then LDS
// reads, then FMAs. Transient-only register use.
__device__ __forceinline__ void gemv256(const float* __restrict__ W,
                                        const float* __restrict__ s_src,
                                        float* __restrict__ s_part,
                                        int sub, int j4)
{
    float4 wv[16];
    float hv[16];
    #pragma unroll
    for (int t = 0; t < 16; ++t)
        wv[t] = *(const float4*)(W + (size_t)(sub + 16 * t) * 256 + j4);
    #pragma unroll
    for (int t = 0; t < 16; ++t)
        hv[t] = s_src[sub + 16 * t];
    float4 a = {0.f, 0.f, 0.f, 0.f};
    #pragma unroll
    for (int t = 0; t < 16; ++t) {
        a.x += hv[t] * wv[t].x; a.y += hv[t] * wv[t].y;
        a.z += hv[t] * wv[t].z; a.w += hv[t] * wv[t].w;
    }
    *(float4*)(&s_part[sub * 256 + j4]) = a;
}

// Main per-row chain: h0, 4 residual layers, wf/tanh, state update, cw0, crw.
__global__ __launch_bounds__(1024, 1) void mlp_main(
    const float* __restrict__ loc, const float* __restrict__ scl,
    const float* __restrict__ hidden, const float* __restrict__ pix,
    const float* __restrict__ w0, const float* __restrict__ b0,
    const float* __restrict__ rw, const float* __restrict__ rb,
    const float* __restrict__ wf, const float* __restrict__ bf,
    const float* __restrict__ cw0, const float* __restrict__ cb0,
    const float* __restrict__ crw, const float* __restrict__ crb,
    float* __restrict__ c1buf, float* __restrict__ out)
{
    __shared__ float s_in[452];
    __shared__ float s_h[256];
    __shared__ float s_c[256];
    __shared__ float s_o[260];
    __shared__ float s_part[16 * 260];
    __shared__ float s_b0[256], s_rb[1024], s_bf[260], s_cb0[256], s_crb[256];

    int b = blockIdx.x, tid = threadIdx.x;
    int jg = tid & 63, sub = tid >> 6;
    int j4 = jg * 4;
    float* orow = out + (size_t)b * OUTROW;

    if (tid < 2) s_in[tid] = loc[2 * b + tid];
    if (tid == 2) s_in[2] = scl[b];
    if (tid >= 256 && tid < 448) s_in[3 + (tid - 256)] = pix[b * 192 + (tid - 256)];
    if (tid >= 512 && tid < 768) s_in[195 + (tid - 512)] = hidden[b * 256 + (tid - 512)];
    if (tid < 256) s_b0[tid] = b0[tid];
    s_rb[tid] = rb[tid];
    if (tid < 259) s_bf[tid] = bf[tid];
    if (tid >= 256 && tid < 512) s_cb0[tid - 256] = cb0[tid - 256];
    if (tid >= 512 && tid < 768) s_crb[tid - 512] = crb[tid - 512];
    __syncthreads();

    // ---- h0 = inp @ w0 + b0 (451 x 256): two 14-deep passes + tail ----
    {
        float4 acc = {0.f, 0.f, 0.f, 0.f};
        {
            float4 wv[14]; float hv[14];
            #pragma unroll
            for (int t = 0; t < 14; ++t)
                wv[t] = *(const float4*)(w0 + (size_t)(sub + 16 * t) * 256 + j4);
            #pragma unroll
            for (int t = 0; t < 14; ++t) hv[t] = s_in[sub + 16 * t];
            #pragma unroll
            for (int t = 0; t < 14; ++t) {
                acc.x += hv[t] * wv[t].x; acc.y += hv[t] * wv[t].y;
                acc.z += hv[t] * wv[t].z; acc.w += hv[t] * wv[t].w;
            }
        }
        {
            float4 wv[14]; float hv[14];
            #pragma unroll
            for (int t = 0; t < 14; ++t)
                wv[t] = *(const float4*)(w0 + (size_t)(sub + 16 * (t + 14)) * 256 + j4);
            #pragma unroll
            for (int t = 0; t < 14; ++t) hv[t] = s_in[sub + 16 * (t + 14)];
            #pragma unroll
            for (int t = 0; t < 14; ++t) {
                acc.x += hv[t] * wv[t].x; acc.y += hv[t] * wv[t].y;
                acc.z += hv[t] * wv[t].z; acc.w += hv[t] * wv[t].w;
            }
        }
        if (sub < 3) {
            int k = 448 + sub;
            float hv = s_in[k];
            float4 w = *(const float4*)(w0 + (size_t)k * 256 + j4);
            acc.x += hv * w.x; acc.y += hv * w.y; acc.z += hv * w.z; acc.w += hv * w.w;
        }
        *(float4*)(&s_part[sub * 256 + j4]) = acc;
    }
    __syncthreads();
    if (tid < 256) {
        float a = s_b0[tid];
        #pragma unroll
        for (int s = 0; s < 16; ++s) a += s_part[s * 256 + tid];
        s_h[tid] = a;
    }
    __syncthreads();

    // ---- 4 residual layers ----
    #pragma unroll 1
    for (int L = 0; L < 4; ++L) {
        gemv256(rw + (size_t)L * 65536, s_h, s_part, sub, j4);
        __syncthreads();
        if (tid < 256) {
            float v = s_rb[L * 256 + tid] + s_h[tid];
            #pragma unroll
            for (int s = 0; s < 16; ++s) v += s_part[s * 256 + tid];
            s_h[tid] = fmaxf(v, 0.f);
        }
        __syncthreads();
    }

    // ---- o = tanh(h @ wf + bf) (256 x 259) ----
    {
        float a0 = 0.f, a1 = 0.f, a2 = 0.f, a3 = 0.f, e = 0.f;
        #pragma unroll 8
        for (int t = 0; t < 16; ++t) {
            int k = sub + 16 * t;
            float hv = s_h[k];
            const float* w = wf + (size_t)k * 259 + j4;
            a0 += hv * w[0]; a1 += hv * w[1]; a2 += hv * w[2]; a3 += hv * w[3];
            if (jg < 3) e += hv * wf[(size_t)k * 259 + 256 + jg];
        }
        s_part[sub * 260 + j4 + 0] = a0;
        s_part[sub * 260 + j4 + 1] = a1;
        s_part[sub * 260 + j4 + 2] = a2;
        s_part[sub * 260 + j4 + 3] = a3;
        if (jg < 3) s_part[sub * 260 + 256 + jg] = e;
    }
    __syncthreads();
    if (tid < 259) {
        float a = s_bf[tid];
        #pragma unroll
        for (int s = 0; s < 16; ++s) a += s_part[s * 260 + tid];
        s_o[tid] = tanhf(a);
    }
    __syncthreads();

    // ---- state update + direct outputs ----
    if (tid < 256) {
        float nh = s_in[195 + tid] + s_o[3 + tid];
        orow[3 + tid] = nh;
        s_h[tid] = nh;
    }
    if (tid == 256) orow[0] = s_in[0] + s_o[0];
    if (tid == 257) orow[1] = s_in[1] + s_o[1];
    if (tid == 258) orow[2] = s_in[2] + s_o[2];
    __syncthreads();

    // ---- c0 = relu(nh @ cw0 + cb0) ----
    gemv256(cw0, s_h, s_part, sub, j4);
    __syncthreads();
    if (tid < 256) {
        float v = s_cb0[tid];
        #pragma unroll
        for (int s = 0; s < 16; ++s) v += s_part[s * 256 + tid];
        s_c[tid] = fmaxf(v, 0.f);
    }
    __syncthreads();

    // ---- c1 = relu(c0 @ crw + crb + c0) -> c1buf ----
    gemv256(crw, s_c, s_part, sub, j4);
    __syncthreads();
    if (tid < 256) {
        float v = s_crb[tid] + s_c[tid];
        #pragma unroll
        for (int s = 0; s < 16; ++s) v += s_part[s * 256 + tid];
        c1buf[b * 256 + tid] = fmaxf(v, 0.f);
    }
}

// logits = c1 @ cw1 + cb1, tiled (row b, col-slice s) over 128x8 blocks.
__global__ __launch_bounds__(1024, 1) void logits_kernel(
    const float* __restrict__ c1buf, const float* __restrict__ cw1,
    const float* __restrict__ cb1, float* __restrict__ logits)
{
    __shared__ float s_c1[256];
    __shared__ float s_part[32 * 128];

    int b = blockIdx.x, s = blockIdx.y, tid = threadIdx.x;
    if (tid < 256) s_c1[tid] = c1buf[b * 256 + tid];
    __syncthreads();

    int cg = tid & 31, sub = tid >> 5;
    int c4 = cg * 4;
    int col0 = s * 128 + c4;
    bool valid = (col0 + 3) < 1000;

    float4 acc = {0.f, 0.f, 0.f, 0.f};
    if (valid) {
        float4 wv[8]; float hv[8];
        #pragma unroll
        for (int t = 0; t < 8; ++t)
            wv[t] = *(const float4*)(cw1 + (size_t)(sub + 32 * t) * 1000 + col0);
        #pragma unroll
        for (int t = 0; t < 8; ++t) hv[t] = s_c1[sub + 32 * t];
        #pragma unroll
        for (int t = 0; t < 8; ++t) {
            acc.x += hv[t] * wv[t].x; acc.y += hv[t] * wv[t].y;
            acc.z += hv[t] * wv[t].z; acc.w += hv[t] * wv[t].w;
        }
    }
    *(float4*)(&s_part[sub * 128 + c4]) = acc;
    __syncthreads();

    if (tid < 128) {
        int col = s * 128 + tid;
        if (col < 1000) {
            float a = cb1[col];
            #pragma unroll
            for (int ss = 0; ss < 32; ++ss) a += s_part[ss * 128 + tid];
            logits[(size_t)b * 1000 + col] = a;
        }
    }
}

// Per-row softmax over 1000 logits -> out[259..1258].
__global__ __launch_bounds__(1024) void softmax_kernel(
    const float* __restrict__ logits, float* __restrict__ out)
{
    __shared__ float s_red[32];
    int b = blockIdx.x, tid = threadIdx.x;
    float* orow = out + (size_t)b * OUTROW;

    float lgv = (tid < 1000) ? logits[(size_t)b * 1000 + tid] : -1e30f;

    int lane = tid & 63, wid = tid >> 6;
    float m = lgv;
    #pragma unroll
    for (int off = 1; off < 64; off <<= 1) m = fmaxf(m, __shfl_xor(m, off));
    if (lane == 0) s_red[wid] = m;
    __syncthreads();
    m = s_red[0];
    #pragma unroll
    for (int w = 1; w < 16; ++w) m = fmaxf(m, s_red[w]);

    float e = (tid < 1000) ? expf(lgv - m) : 0.f;
    float lsum = e;
    #pragma unroll
    for (int off = 1; off < 64; off <<= 1) lsum += __shfl_xor(lsum, off);
    if (lane == 0) s_red[16 + wid] = lsum;
    __syncthreads();
    float total = 0.f;
    #pragma unroll
    for (int w = 0; w < 16; ++w) total += s_red[16 + w];

    if (tid < 1000) orow[259 + tid] = e / total;
}

extern "C" void kernel_launch(void* const* d_in, const int* in_sizes, int n_in,
                              void* d_out, int out_size, void* d_ws, size_t ws_size,
                              hipStream_t stream) {
    const float* image  = (const float*)d_in[0];
    const float* loc    = (const float*)d_in[1];
    const float* scl    = (const float*)d_in[2];
    const float* hidden = (const float*)d_in[3];
    const float* w0  = (const float*)d_in[4];
    const float* b0  = (const float*)d_in[5];
    const float* rw  = (const float*)d_in[6];
    const float* rb  = (const float*)d_in[7];
    const float* wf  = (const float*)d_in[8];
    const float* bf  = (const float*)d_in[9];
    const float* cw0 = (const float*)d_in[10];
    const float* cb0 = (const float*)d_in[11];
    const float* crw = (const float*)d_in[12];
    const float* crb = (const float*)d_in[13];
    const float* cw1 = (const float*)d_in[14];
    const float* cb1 = (const float*)d_in[15];

    float* ws     = (float*)d_ws;
    float* pix    = ws;                 // 128*192
    float* c1buf  = ws + 24576;         // 128*256
    float* logits = ws + 24576 + 32768; // 128*1000
    float* sink   = ws + 24576 + 32768 + 128000;

    hipLaunchKernelGGL(interp_kernel, dim3(BB * 3), dim3(256), 0, stream,
                       image, loc, scl, pix);
    hipLaunchKernelGGL(warm_l2, dim3(256), dim3(256), 0, stream,
                       w0, rw, wf, cw0, crw, sink);
    hipLaunchKernelGGL(mlp_main, dim3(BB), dim3(1024), 0, stream,
                       loc, scl, hidden, pix,
                       w0, b0, rw, rb, wf, bf, cw0, cb0, crw, crb,
                       c1buf, (float*)d_out);
    hipLaunchKernelGGL(logits_kernel, dim3(BB, 8), dim3(1024), 0, stream,
                       c1buf, cw1, cb1, logits);
    hipLaunchKernelGGL(softmax_kernel, dim3(BB), dim3(1024), 0, stream,
                       logits, (float*)d_out);
}

// Round 9
// 87.780 us; speedup vs baseline: 1.0114x; 1.0114x over previous
//
#include <hip/hip_runtime.h>
#include <math.h>

#define BB 128
#define OUTROW 1259   // 2+1+256+1000

typedef float vf4 __attribute__((ext_vector_type(4)));

// ---------------- bf16 helpers ----------------
__device__ __forceinline__ ushort f2b(float x) {
    unsigned u = __float_as_uint(x);
    unsigned r = (u + 0x7FFFu + ((u >> 16) & 1u)) >> 16;   // round-to-nearest-even
    return (ushort)r;
}
__device__ __forceinline__ float b2f(ushort b) {
    return __uint_as_float(((unsigned)b) << 16);
}
__device__ __forceinline__ float4 bf4tof(ushort4 u) {
    float4 f;
    f.x = __uint_as_float((unsigned)u.x << 16);
    f.y = __uint_as_float((unsigned)u.y << 16);
    f.z = __uint_as_float((unsigned)u.z << 16);
    f.w = __uint_as_float((unsigned)u.w << 16);
    return f;
}

// bf16 arena layout (ushort offsets within arena)
#define OFF_W0   0u        // 451*256 = 115456
#define OFF_RW   115456u   // 4*65536 = 262144
#define OFF_CW0  377600u   // 65536
#define OFF_CRW  443136u   // 65536
#define OFF_CW1  508672u   // 256000
#define OFF_WF   764672u   // 256*260 = 66560 (padded stride 260)
#define N_CONV   831232u

// A(t) = sin(H*pi*r)*cos(pi*r)/(H*sin(pi*r)),  B(t) = sin(H*pi*r)/H,  r = t - round(t)
__device__ __forceinline__ void dirichlet_ab(float t, float& A, float& Bv) {
    float r = t - rintf(t);
    float s256 = sinpif(256.0f * r);
    Bv = s256 * (1.0f / 256.0f);
    if (fabsf(r) < 1e-6f) {
        A = 1.0f;
    } else {
        float sp = sinpif(r), cp = cospif(r);
        A = Bv * cp / sp;
    }
}

// Fused: blocks 0..383 do NUDFT interp (one block per (b,c)); blocks 384+
// convert all weight matrices to bf16 in d_ws (runs every call, deterministic).
__global__ __launch_bounds__(256) void interp_convert_kernel(
    const float* __restrict__ image, const float* __restrict__ loc,
    const float* __restrict__ scl, float* __restrict__ pix,
    const float* __restrict__ w0, const float* __restrict__ rw,
    const float* __restrict__ wf, const float* __restrict__ cw0,
    const float* __restrict__ crw, const float* __restrict__ cw1,
    ushort* __restrict__ bfa)
{
    __shared__ float U[256 * 16];
    __shared__ float V[16 * 260];
    __shared__ float T[16 * 260];

    int bid = blockIdx.x;
    int tid = threadIdx.x;

    if (bid >= 384) {
        // ---- weight conversion ----
        unsigned g = (unsigned)(bid - 384) * 256u + (unsigned)tid;
        for (unsigned i = g; i < N_CONV; i += 2048u * 256u) {
            unsigned j = i; float v;
            if (j < 115456u) { v = w0[j]; bfa[OFF_W0 + j] = f2b(v); continue; }
            j -= 115456u;
            if (j < 262144u) { v = rw[j]; bfa[OFF_RW + j] = f2b(v); continue; }
            j -= 262144u;
            if (j < 65536u) { v = cw0[j]; bfa[OFF_CW0 + j] = f2b(v); continue; }
            j -= 65536u;
            if (j < 65536u) { v = crw[j]; bfa[OFF_CRW + j] = f2b(v); continue; }
            j -= 65536u;
            if (j < 256000u) { v = cw1[j]; bfa[OFF_CW1 + j] = f2b(v); continue; }
            j -= 256000u;
            { // wf padded to stride 260
                unsigned k = j / 260u, c = j - k * 260u;
                bfa[OFF_WF + j] = (c < 259u) ? f2b(wf[k * 259u + c]) : (ushort)0;
            }
        }
        return;
    }

    int b = bid / 3, c = bid % 3;
    float l0 = loc[2 * b], l1 = loc[2 * b + 1], sc = scl[b];

    {
        int p = tid;
        float tp = (float)p * (1.0f / 256.0f);
        #pragma unroll
        for (int iy = 0; iy < 8; ++iy) {
            float A, Bv;
            float y = ((float)iy * 0.125f - l0) * sc;
            dirichlet_ab(y - tp, A, Bv);
            int w = iy >> 1, o = iy & 1;
            U[p * 16 + w * 4 + o] = A;
            U[p * 16 + w * 4 + 2 + o] = Bv;
            float x = ((float)iy * 0.125f - l1) * sc;
            dirichlet_ab(x - tp, A, Bv);
            V[iy * 260 + p] = A;
            V[(8 + iy) * 260 + p] = Bv;
        }
    }
    __syncthreads();

    int wave = tid >> 6, lane = tid & 63;
    const float* img = image + (size_t)(b * 3 + c) * 65536 + lane * 4;

    float aA0[4] = {0, 0, 0, 0}, aA1[4] = {0, 0, 0, 0};
    float aB0[4] = {0, 0, 0, 0}, aB1[4] = {0, 0, 0, 0};
    #pragma unroll 4
    for (int p = 0; p < 256; ++p) {
        vf4 v = __builtin_nontemporal_load((const vf4*)(img + p * 256));
        const float4 u = *(const float4*)(&U[p * 16 + wave * 4]);
        aA0[0] += u.x * v[0]; aA0[1] += u.x * v[1]; aA0[2] += u.x * v[2]; aA0[3] += u.x * v[3];
        aA1[0] += u.y * v[0]; aA1[1] += u.y * v[1]; aA1[2] += u.y * v[2]; aA1[3] += u.y * v[3];
        aB0[0] += u.z * v[0]; aB0[1] += u.z * v[1]; aB0[2] += u.z * v[2]; aB0[3] += u.z * v[3];
        aB1[0] += u.w * v[0]; aB1[1] += u.w * v[1]; aB1[2] += u.w * v[2]; aB1[3] += u.w * v[3];
    }
    int iy0 = wave * 2;
    int q0 = lane * 4;
    #pragma unroll
    for (int j = 0; j < 4; ++j) {
        T[iy0 * 260 + q0 + j]       = aA0[j];
        T[(iy0 + 1) * 260 + q0 + j] = aA1[j];
        T[(8 + iy0) * 260 + q0 + j]     = aB0[j];
        T[(8 + iy0 + 1) * 260 + q0 + j] = aB1[j];
    }
    __syncthreads();

    int n = tid >> 2, sub = tid & 3;
    int iy = n >> 3, ix = n & 7;
    float s = 0.f;
    #pragma unroll 8
    for (int i = 0; i < 64; ++i) {
        int q = sub + 4 * i;
        s += T[iy * 260 + q] * V[ix * 260 + q] - T[(8 + iy) * 260 + q] * V[(8 + ix) * 260 + q];
    }
    s += __shfl_xor(s, 1);
    s += __shfl_xor(s, 2);
    if (sub == 0) pix[(b * 64 + n) * 3 + c] = s;
}

// 256x256 GEMV piece with bf16 weights: 16 ushort4 loads batched, then FMAs.
__device__ __forceinline__ void gemv256b(const ushort* __restrict__ W,
                                         const float* __restrict__ s_src,
                                         float* __restrict__ s_part,
                                         int sub, int j4)
{
    ushort4 wv[16];
    float hv[16];
    #pragma unroll
    for (int t = 0; t < 16; ++t)
        wv[t] = *(const ushort4*)(W + (size_t)(sub + 16 * t) * 256 + j4);
    #pragma unroll
    for (int t = 0; t < 16; ++t)
        hv[t] = s_src[sub + 16 * t];
    float4 a = {0.f, 0.f, 0.f, 0.f};
    #pragma unroll
    for (int t = 0; t < 16; ++t) {
        float4 w = bf4tof(wv[t]);
        a.x += hv[t] * w.x; a.y += hv[t] * w.y;
        a.z += hv[t] * w.z; a.w += hv[t] * w.w;
    }
    *(float4*)(&s_part[sub * 256 + j4]) = a;
}

// Main per-row chain, bf16 weights: h0, 4 residual, wf/tanh, update, cw0, crw.
__global__ __launch_bounds__(1024, 1) void mlp_main(
    const float* __restrict__ loc, const float* __restrict__ scl,
    const float* __restrict__ hidden, const float* __restrict__ pix,
    const ushort* __restrict__ bfa,
    const float* __restrict__ b0, const float* __restrict__ rb,
    const float* __restrict__ bf, const float* __restrict__ cb0,
    const float* __restrict__ crb,
    float* __restrict__ c1buf, float* __restrict__ out)
{
    __shared__ float s_in[452];
    __shared__ float s_h[256];
    __shared__ float s_c[256];
    __shared__ float s_o[260];
    __shared__ float s_part[16 * 260];
    __shared__ float s_b0[256], s_rb[1024], s_bf[260], s_cb0[256], s_crb[256];

    const ushort* w0b  = bfa + OFF_W0;
    const ushort* rwb  = bfa + OFF_RW;
    const ushort* wfb  = bfa + OFF_WF;
    const ushort* cw0b = bfa + OFF_CW0;
    const ushort* crwb = bfa + OFF_CRW;

    int b = blockIdx.x, tid = threadIdx.x;
    int jg = tid & 63, sub = tid >> 6;
    int j4 = jg * 4;
    float* orow = out + (size_t)b * OUTROW;

    if (tid < 2) s_in[tid] = loc[2 * b + tid];
    if (tid == 2) s_in[2] = scl[b];
    if (tid >= 256 && tid < 448) s_in[3 + (tid - 256)] = pix[b * 192 + (tid - 256)];
    if (tid >= 512 && tid < 768) s_in[195 + (tid - 512)] = hidden[b * 256 + (tid - 512)];
    if (tid < 256) s_b0[tid] = b0[tid];
    s_rb[tid] = rb[tid];
    if (tid < 259) s_bf[tid] = bf[tid];
    if (tid >= 256 && tid < 512) s_cb0[tid - 256] = cb0[tid - 256];
    if (tid >= 512 && tid < 768) s_crb[tid - 512] = crb[tid - 512];
    __syncthreads();

    // ---- h0 = inp @ w0 + b0 (451 x 256): two 14-deep passes + tail ----
    {
        float4 acc = {0.f, 0.f, 0.f, 0.f};
        {
            ushort4 wv[14]; float hv[14];
            #pragma unroll
            for (int t = 0; t < 14; ++t)
                wv[t] = *(const ushort4*)(w0b + (size_t)(sub + 16 * t) * 256 + j4);
            #pragma unroll
            for (int t = 0; t < 14; ++t) hv[t] = s_in[sub + 16 * t];
            #pragma unroll
            for (int t = 0; t < 14; ++t) {
                float4 w = bf4tof(wv[t]);
                acc.x += hv[t] * w.x; acc.y += hv[t] * w.y;
                acc.z += hv[t] * w.z; acc.w += hv[t] * w.w;
            }
        }
        {
            ushort4 wv[14]; float hv[14];
            #pragma unroll
            for (int t = 0; t < 14; ++t)
                wv[t] = *(const ushort4*)(w0b + (size_t)(sub + 16 * (t + 14)) * 256 + j4);
            #pragma unroll
            for (int t = 0; t < 14; ++t) hv[t] = s_in[sub + 16 * (t + 14)];
            #pragma unroll
            for (int t = 0; t < 14; ++t) {
                float4 w = bf4tof(wv[t]);
                acc.x += hv[t] * w.x; acc.y += hv[t] * w.y;
                acc.z += hv[t] * w.z; acc.w += hv[t] * w.w;
            }
        }
        if (sub < 3) {
            int k = 448 + sub;
            float hv = s_in[k];
            float4 w = bf4tof(*(const ushort4*)(w0b + (size_t)k * 256 + j4));
            acc.x += hv * w.x; acc.y += hv * w.y; acc.z += hv * w.z; acc.w += hv * w.w;
        }
        *(float4*)(&s_part[sub * 256 + j4]) = acc;
    }
    __syncthreads();
    if (tid < 256) {
        float a = s_b0[tid];
        #pragma unroll
        for (int s = 0; s < 16; ++s) a += s_part[s * 256 + tid];
        s_h[tid] = a;
    }
    __syncthreads();

    // ---- 4 residual layers ----
    #pragma unroll 1
    for (int L = 0; L < 4; ++L) {
        gemv256b(rwb + (size_t)L * 65536, s_h, s_part, sub, j4);
        __syncthreads();
        if (tid < 256) {
            float v = s_rb[L * 256 + tid] + s_h[tid];
            #pragma unroll
            for (int s = 0; s < 16; ++s) v += s_part[s * 256 + tid];
            s_h[tid] = fmaxf(v, 0.f);
        }
        __syncthreads();
    }

    // ---- o = tanh(h @ wf + bf) (256 x 260-padded) ----
    {
        float a0 = 0.f, a1 = 0.f, a2 = 0.f, a3 = 0.f, e = 0.f;
        ushort4 wv[16]; float hv[16]; ushort ev[16];
        #pragma unroll
        for (int t = 0; t < 16; ++t) {
            int k = sub + 16 * t;
            wv[t] = *(const ushort4*)(wfb + (size_t)k * 260 + j4);
            if (jg < 3) ev[t] = wfb[(size_t)k * 260 + 256 + jg];
        }
        #pragma unroll
        for (int t = 0; t < 16; ++t) hv[t] = s_h[sub + 16 * t];
        #pragma unroll
        for (int t = 0; t < 16; ++t) {
            float4 w = bf4tof(wv[t]);
            a0 += hv[t] * w.x; a1 += hv[t] * w.y; a2 += hv[t] * w.z; a3 += hv[t] * w.w;
            if (jg < 3) e += hv[t] * b2f(ev[t]);
        }
        s_part[sub * 260 + j4 + 0] = a0;
        s_part[sub * 260 + j4 + 1] = a1;
        s_part[sub * 260 + j4 + 2] = a2;
        s_part[sub * 260 + j4 + 3] = a3;
        if (jg < 3) s_part[sub * 260 + 256 + jg] = e;
    }
    __syncthreads();
    if (tid < 259) {
        float a = s_bf[tid];
        #pragma unroll
        for (int s = 0; s < 16; ++s) a += s_part[s * 260 + tid];
        s_o[tid] = tanhf(a);
    }
    __syncthreads();

    // ---- state update + direct outputs ----
    if (tid < 256) {
        float nh = s_in[195 + tid] + s_o[3 + tid];
        orow[3 + tid] = nh;
        s_h[tid] = nh;
    }
    if (tid == 256) orow[0] = s_in[0] + s_o[0];
    if (tid == 257) orow[1] = s_in[1] + s_o[1];
    if (tid == 258) orow[2] = s_in[2] + s_o[2];
    __syncthreads();

    // ---- c0 = relu(nh @ cw0 + cb0) ----
    gemv256b(cw0b, s_h, s_part, sub, j4);
    __syncthreads();
    if (tid < 256) {
        float v = s_cb0[tid];
        #pragma unroll
        for (int s = 0; s < 16; ++s) v += s_part[s * 256 + tid];
        s_c[tid] = fmaxf(v, 0.f);
    }
    __syncthreads();

    // ---- c1 = relu(c0 @ crw + crb + c0) -> c1buf ----
    gemv256b(crwb, s_c, s_part, sub, j4);
    __syncthreads();
    if (tid < 256) {
        float v = s_crb[tid] + s_c[tid];
        #pragma unroll
        for (int s = 0; s < 16; ++s) v += s_part[s * 256 + tid];
        c1buf[b * 256 + tid] = fmaxf(v, 0.f);
    }
}

// logits = c1 @ cw1 + cb1 (bf16 weights), tiled (row b, col-slice s), 128x8 blocks.
__global__ __launch_bounds__(1024, 1) void logits_kernel(
    const float* __restrict__ c1buf, const ushort* __restrict__ bfa,
    const float* __restrict__ cb1, float* __restrict__ logits)
{
    __shared__ float s_c1[256];
    __shared__ float s_part[32 * 128];

    const ushort* cw1b = bfa + OFF_CW1;

    int b = blockIdx.x, s = blockIdx.y, tid = threadIdx.x;
    if (tid < 256) s_c1[tid] = c1buf[b * 256 + tid];
    __syncthreads();

    int cg = tid & 31, sub = tid >> 5;
    int c4 = cg * 4;
    int col0 = s * 128 + c4;
    bool valid = (col0 + 3) < 1000;

    float4 acc = {0.f, 0.f, 0.f, 0.f};
    if (valid) {
        ushort4 wv[8]; float hv[8];
        #pragma unroll
        for (int t = 0; t < 8; ++t)
            wv[t] = *(const ushort4*)(cw1b + (size_t)(sub + 32 * t) * 1000 + col0);
        #pragma unroll
        for (int t = 0; t < 8; ++t) hv[t] = s_c1[sub + 32 * t];
        #pragma unroll
        for (int t = 0; t < 8; ++t) {
            float4 w = bf4tof(wv[t]);
            acc.x += hv[t] * w.x; acc.y += hv[t] * w.y;
            acc.z += hv[t] * w.z; acc.w += hv[t] * w.w;
        }
    }
    *(float4*)(&s_part[sub * 128 + c4]) = acc;
    __syncthreads();

    if (tid < 128) {
        int col = s * 128 + tid;
        if (col < 1000) {
            float a = cb1[col];
            #pragma unroll
            for (int ss = 0; ss < 32; ++ss) a += s_part[ss * 128 + tid];
            logits[(size_t)b * 1000 + col] = a;
        }
    }
}

// Per-row softmax over 1000 logits -> out[259..1258].
__global__ __launch_bounds__(1024) void softmax_kernel(
    const float* __restrict__ logits, float* __restrict__ out)
{
    __shared__ float s_red[32];
    int b = blockIdx.x, tid = threadIdx.x;
    float* orow = out + (size_t)b * OUTROW;

    float lgv = (tid < 1000) ? logits[(size_t)b * 1000 + tid] : -1e30f;

    int lane = tid & 63, wid = tid >> 6;
    float m = lgv;
    #pragma unroll
    for (int off = 1; off < 64; off <<= 1) m = fmaxf(m, __shfl_xor(m, off));
    if (lane == 0) s_red[wid] = m;
    __syncthreads();
    m = s_red[0];
    #pragma unroll
    for (int w = 1; w < 16; ++w) m = fmaxf(m, s_red[w]);

    float e = (tid < 1000) ? expf(lgv - m) : 0.f;
    float lsum = e;
    #pragma unroll
    for (int off = 1; off < 64; off <<= 1) lsum += __shfl_xor(lsum, off);
    if (lane == 0) s_red[16 + wid] = lsum;
    __syncthreads();
    float total = 0.f;
    #pragma unroll
    for (int w = 0; w < 16; ++w) total += s_red[16 + w];

    if (tid < 1000) orow[259 + tid] = e / total;
}

extern "C" void kernel_launch(void* const* d_in, const int* in_sizes, int n_in,
                              void* d_out, int out_size, void* d_ws, size_t ws_size,
                              hipStream_t stream) {
    const float* image  = (const float*)d_in[0];
    const float* loc    = (const float*)d_in[1];
    const float* scl    = (const float*)d_in[2];
    const float* hidden = (const float*)d_in[3];
    const float* w0  = (const float*)d_in[4];
    const float* b0  = (const float*)d_in[5];
    const float* rw  = (const float*)d_in[6];
    const float* rb  = (const float*)d_in[7];
    const float* wf  = (const float*)d_in[8];
    const float* bf  = (const float*)d_in[9];
    const float* cw0 = (const float*)d_in[10];
    const float* cb0 = (const float*)d_in[11];
    const float* crw = (const float*)d_in[12];
    const float* crb = (const float*)d_in[13];
    const float* cw1 = (const float*)d_in[14];
    const float* cb1 = (const float*)d_in[15];

    float* ws     = (float*)d_ws;
    float* pix    = ws;                     // 24576 floats
    float* c1buf  = ws + 24576;             // 32768 floats
    float* logits = ws + 24576 + 32768;     // 128000 floats
    ushort* bfa   = (ushort*)(ws + 185344); // 831232 ushorts (bf16 arena)

    hipLaunchKernelGGL(interp_convert_kernel, dim3(384 + 2048), dim3(256), 0, stream,
                       image, loc, scl, pix, w0, rw, wf, cw0, crw, cw1, bfa);
    hipLaunchKernelGGL(mlp_main, dim3(BB), dim3(1024), 0, stream,
                       loc, scl, hidden, pix, bfa,
                       b0, rb, bf, cb0, crb, c1buf, (float*)d_out);
    hipLaunchKernelGGL(logits_kernel, dim3(BB, 8), dim3(1024), 0, stream,
                       c1buf, bfa, cb1, logits);
    hipLaunchKernelGGL(softmax_kernel, dim3(BB), dim3(1024), 0, stream,
                       logits, (float*)d_out);
}

// Round 10
// 74.307 us; speedup vs baseline: 1.1948x; 1.1813x over previous
//
#include <hip/hip_runtime.h>
#include <math.h>

#define BB 128
#define OUTROW 1259   // 2+1+256+1000

typedef float vf4 __attribute__((ext_vector_type(4)));

// ---------------- bf16 helpers ----------------
__device__ __forceinline__ ushort f2b(float x) {
    unsigned u = __float_as_uint(x);
    unsigned r = (u + 0x7FFFu + ((u >> 16) & 1u)) >> 16;   // RNE
    return (ushort)r;
}
__device__ __forceinline__ uint pack2(float lo, float hi) {
    return (uint)f2b(lo) | ((uint)f2b(hi) << 16);
}
// D = a.bf16[0]*b.bf16[0] + a.bf16[1]*b.bf16[1] + c   (f32 accumulate)
__device__ __forceinline__ float dot2bf(uint a, uint b, float c) {
    float d;
    asm("v_dot2_f32_bf16 %0, %1, %2, %3" : "=v"(d) : "v"(a), "v"(b), "v"(c));
    return d;
}

// bf16 arena: pair-interleaved layout W2[k/2][col][2] (ushort offsets)
#define OFF_W0   0u        // 240 kp * 512          = 122880  (k padded 451->480)
#define OFF_RW   122880u   // 4 layers * 128kp*512  = 262144
#define OFF_CW0  385024u   // 128*512               = 65536
#define OFF_CRW  450560u   // 128*512               = 65536
#define OFF_WF   516096u   // 128 kp * 520 (260c)   = 66560   (col 259 zero-pad)
#define OFF_CW1  582656u   // 128 kp * 2000 (1000c) = 256000
#define N_TOT    838656u

// A(t) = sin(H*pi*r)*cos(pi*r)/(H*sin(pi*r)),  B(t) = sin(H*pi*r)/H
__device__ __forceinline__ void dirichlet_ab(float t, float& A, float& Bv) {
    float r = t - rintf(t);
    float s256 = sinpif(256.0f * r);
    Bv = s256 * (1.0f / 256.0f);
    if (fabsf(r) < 1e-6f) {
        A = 1.0f;
    } else {
        float sp = sinpif(r), cp = cospif(r);
        A = Bv * cp / sp;
    }
}

// blocks 0..383: NUDFT interp (one per (b,c)); blocks 384+: bf16 pair-convert.
__global__ __launch_bounds__(256) void interp_convert_kernel(
    const float* __restrict__ image, const float* __restrict__ loc,
    const float* __restrict__ scl, float* __restrict__ pix,
    const float* __restrict__ w0, const float* __restrict__ rw,
    const float* __restrict__ wf, const float* __restrict__ cw0,
    const float* __restrict__ crw, const float* __restrict__ cw1,
    ushort* __restrict__ bfa)
{
    __shared__ float U[256 * 16];
    __shared__ float V[16 * 260];
    __shared__ float T[16 * 260];

    int bid = blockIdx.x;
    int tid = threadIdx.x;

    if (bid >= 384) {
        unsigned g = (unsigned)(bid - 384) * 256u + (unsigned)tid;
        for (unsigned i = g; i < N_TOT; i += 512u * 256u) {
            unsigned j = i;
            if (j < 122880u) {                     // w0: C=256, 451 real rows
                unsigned kp = j >> 9, r = j & 511u, c = r >> 1, k = 2u*kp + (r & 1u);
                bfa[OFF_W0 + j] = (k < 451u) ? f2b(w0[k * 256u + c]) : (ushort)0;
            } else if (j < 385024u) {              // rw: 1024 rows x 256
                unsigned jj = j - 122880u;
                unsigned kp = jj >> 9, r = jj & 511u, c = r >> 1, k = 2u*kp + (r & 1u);
                bfa[OFF_RW + jj] = f2b(rw[k * 256u + c]);
            } else if (j < 450560u) {              // cw0
                unsigned jj = j - 385024u;
                unsigned kp = jj >> 9, r = jj & 511u, c = r >> 1, k = 2u*kp + (r & 1u);
                bfa[OFF_CW0 + jj] = f2b(cw0[k * 256u + c]);
            } else if (j < 516096u) {              // crw
                unsigned jj = j - 450560u;
                unsigned kp = jj >> 9, r = jj & 511u, c = r >> 1, k = 2u*kp + (r & 1u);
                bfa[OFF_CRW + jj] = f2b(crw[k * 256u + c]);
            } else if (j < 582656u) {              // wf: pitch 260 cols, 259 real
                unsigned jj = j - 516096u;
                unsigned kp = jj / 520u, r = jj - kp * 520u, c = r >> 1, k = 2u*kp + (r & 1u);
                bfa[OFF_WF + jj] = (c < 259u) ? f2b(wf[k * 259u + c]) : (ushort)0;
            } else {                               // cw1: 1000 cols
                unsigned jj = j - 582656u;
                unsigned kp = jj / 2000u, r = jj - kp * 2000u, c = r >> 1, k = 2u*kp + (r & 1u);
                bfa[OFF_CW1 + jj] = f2b(cw1[k * 1000u + c]);
            }
        }
        return;
    }

    int b = bid / 3, c = bid % 3;
    float l0 = loc[2 * b], l1 = loc[2 * b + 1], sc = scl[b];

    {
        int p = tid;
        float tp = (float)p * (1.0f / 256.0f);
        #pragma unroll
        for (int iy = 0; iy < 8; ++iy) {
            float A, Bv;
            float y = ((float)iy * 0.125f - l0) * sc;
            dirichlet_ab(y - tp, A, Bv);
            int w = iy >> 1, o = iy & 1;
            U[p * 16 + w * 4 + o] = A;
            U[p * 16 + w * 4 + 2 + o] = Bv;
            float x = ((float)iy * 0.125f - l1) * sc;
            dirichlet_ab(x - tp, A, Bv);
            V[iy * 260 + p] = A;
            V[(8 + iy) * 260 + p] = Bv;
        }
    }
    __syncthreads();

    int wave = tid >> 6, lane = tid & 63;
    const float* img = image + (size_t)(b * 3 + c) * 65536 + lane * 4;

    float aA0[4] = {0, 0, 0, 0}, aA1[4] = {0, 0, 0, 0};
    float aB0[4] = {0, 0, 0, 0}, aB1[4] = {0, 0, 0, 0};
    #pragma unroll 4
    for (int p = 0; p < 256; ++p) {
        vf4 v = __builtin_nontemporal_load((const vf4*)(img + p * 256));
        const float4 u = *(const float4*)(&U[p * 16 + wave * 4]);
        aA0[0] += u.x * v[0]; aA0[1] += u.x * v[1]; aA0[2] += u.x * v[2]; aA0[3] += u.x * v[3];
        aA1[0] += u.y * v[0]; aA1[1] += u.y * v[1]; aA1[2] += u.y * v[2]; aA1[3] += u.y * v[3];
        aB0[0] += u.z * v[0]; aB0[1] += u.z * v[1]; aB0[2] += u.z * v[2]; aB0[3] += u.z * v[3];
        aB1[0] += u.w * v[0]; aB1[1] += u.w * v[1]; aB1[2] += u.w * v[2]; aB1[3] += u.w * v[3];
    }
    int iy0 = wave * 2;
    int q0 = lane * 4;
    #pragma unroll
    for (int j = 0; j < 4; ++j) {
        T[iy0 * 260 + q0 + j]       = aA0[j];
        T[(iy0 + 1) * 260 + q0 + j] = aA1[j];
        T[(8 + iy0) * 260 + q0 + j]     = aB0[j];
        T[(8 + iy0 + 1) * 260 + q0 + j] = aB1[j];
    }
    __syncthreads();

    int n = tid >> 2, sub = tid & 3;
    int iy = n >> 3, ix = n & 7;
    float s = 0.f;
    #pragma unroll 8
    for (int i = 0; i < 64; ++i) {
        int q = sub + 4 * i;
        s += T[iy * 260 + q] * V[ix * 260 + q] - T[(8 + iy) * 260 + q] * V[(8 + ix) * 260 + q];
    }
    s += __shfl_xor(s, 1);
    s += __shfl_xor(s, 2);
    if (sub == 0) pix[(b * 64 + n) * 3 + c] = s;
}

// Monolithic per-row MLP with pair-interleaved bf16 weights + v_dot2_f32_bf16.
// Thread map for 256-col layers: jg = tid&63 owns cols 4jg..4jg+3;
// sub = tid>>6 owns k-pairs kp = sub+16t. One uint4 load = 4 cols x 1 k-pair.
__global__ __launch_bounds__(1024, 1) void mlp_fused(
    const float* __restrict__ loc, const float* __restrict__ scl,
    const float* __restrict__ hidden, const float* __restrict__ pix,
    const ushort* __restrict__ bfa,
    const float* __restrict__ b0, const float* __restrict__ rb,
    const float* __restrict__ bf, const float* __restrict__ cb0,
    const float* __restrict__ crb, const float* __restrict__ cb1,
    float* __restrict__ out)
{
    __shared__ float s_in[480];
    __shared__ float s_h[256];
    __shared__ float s_c[256];
    __shared__ float s_o[260];
    __shared__ float s_part[16 * 260];
    __shared__ float s_lg[1024];
    __shared__ uint  s_in2[240];
    __shared__ uint  s_hb2[128];
    __shared__ uint  s_cb2[128];
    __shared__ float s_b0[256], s_rb[1024], s_bf[260], s_cb0[256], s_crb[256], s_cb1[1000];
    __shared__ float s_red[32];

    int b = blockIdx.x, tid = threadIdx.x;
    int jg = tid & 63, sub = tid >> 6;
    int j4 = jg * 4;
    float* orow = out + (size_t)b * OUTROW;

    // ---- stage inputs + biases ----
    if (tid < 2) s_in[tid] = loc[2 * b + tid];
    if (tid == 2) s_in[2] = scl[b];
    if (tid >= 256 && tid < 448) s_in[3 + (tid - 256)] = pix[b * 192 + (tid - 256)];
    if (tid >= 512 && tid < 768) s_in[195 + (tid - 512)] = hidden[b * 256 + (tid - 512)];
    if (tid >= 768 && tid < 797) s_in[451 + (tid - 768)] = 0.f;   // pad 451..479
    if (tid < 256) s_b0[tid] = b0[tid];
    s_rb[tid] = rb[tid];
    if (tid < 259) s_bf[tid] = bf[tid];
    if (tid >= 256 && tid < 512) s_cb0[tid - 256] = cb0[tid - 256];
    if (tid >= 512 && tid < 768) s_crb[tid - 512] = crb[tid - 512];
    if (tid < 1000) s_cb1[tid] = cb1[tid];
    __syncthreads();
    if (tid < 240) s_in2[tid] = pack2(s_in[2 * tid], s_in[2 * tid + 1]);
    __syncthreads();

    const ushort* w0b  = bfa + OFF_W0;
    const ushort* rwb  = bfa + OFF_RW;
    const ushort* cw0b = bfa + OFF_CW0;
    const ushort* crwb = bfa + OFF_CRW;
    const ushort* wfb  = bfa + OFF_WF;
    const ushort* cw1b = bfa + OFF_CW1;

    // ---- h0 = inp @ w0 + b0 (240 k-pairs, 15 per sub) ----
    {
        uint4 wv[15]; uint hv[15];
        #pragma unroll
        for (int t = 0; t < 15; ++t)
            wv[t] = *(const uint4*)(w0b + (size_t)(sub + 16 * t) * 512 + jg * 8);
        #pragma unroll
        for (int t = 0; t < 15; ++t) hv[t] = s_in2[sub + 16 * t];
        vf4 a = {0.f, 0.f, 0.f, 0.f};
        #pragma unroll
        for (int t = 0; t < 15; ++t) {
            a[0] = dot2bf(wv[t].x, hv[t], a[0]);
            a[1] = dot2bf(wv[t].y, hv[t], a[1]);
            a[2] = dot2bf(wv[t].z, hv[t], a[2]);
            a[3] = dot2bf(wv[t].w, hv[t], a[3]);
        }
        *(vf4*)(&s_part[sub * 256 + j4]) = a;
    }
    __syncthreads();
    if (tid < 256) {
        float v = s_b0[tid];
        #pragma unroll
        for (int s = 0; s < 16; ++s) v += s_part[s * 256 + tid];
        s_h[tid] = v;
        float v2 = __shfl_xor(v, 1);
        if (!(tid & 1)) s_hb2[tid >> 1] = pack2(v, v2);
    }
    __syncthreads();

    // ---- 4 residual layers: h = relu(h@rw + rb + h) ----
    #pragma unroll 1
    for (int L = 0; L < 4; ++L) {
        const ushort* W = rwb + (size_t)L * 65536;
        {
            uint4 wv[8]; uint hv[8];
            #pragma unroll
            for (int t = 0; t < 8; ++t)
                wv[t] = *(const uint4*)(W + (size_t)(sub + 16 * t) * 512 + jg * 8);
            #pragma unroll
            for (int t = 0; t < 8; ++t) hv[t] = s_hb2[sub + 16 * t];
            vf4 a = {0.f, 0.f, 0.f, 0.f};
            #pragma unroll
            for (int t = 0; t < 8; ++t) {
                a[0] = dot2bf(wv[t].x, hv[t], a[0]);
                a[1] = dot2bf(wv[t].y, hv[t], a[1]);
                a[2] = dot2bf(wv[t].z, hv[t], a[2]);
                a[3] = dot2bf(wv[t].w, hv[t], a[3]);
            }
            *(vf4*)(&s_part[sub * 256 + j4]) = a;
        }
        __syncthreads();
        if (tid < 256) {
            float v = s_rb[L * 256 + tid] + s_h[tid];
            #pragma unroll
            for (int s = 0; s < 16; ++s) v += s_part[s * 256 + tid];
            v = fmaxf(v, 0.f);
            s_h[tid] = v;
            float v2 = __shfl_xor(v, 1);
            if (!(tid & 1)) s_hb2[tid >> 1] = pack2(v, v2);
        }
        __syncthreads();
    }

    // ---- o = tanh(h @ wf + bf) (260-col padded) ----
    {
        uint4 wv[8]; uint hv[8];
        #pragma unroll
        for (int t = 0; t < 8; ++t)
            wv[t] = *(const uint4*)(wfb + (size_t)(sub + 16 * t) * 520 + jg * 8);
        #pragma unroll
        for (int t = 0; t < 8; ++t) hv[t] = s_hb2[sub + 16 * t];
        vf4 a = {0.f, 0.f, 0.f, 0.f};
        #pragma unroll
        for (int t = 0; t < 8; ++t) {
            a[0] = dot2bf(wv[t].x, hv[t], a[0]);
            a[1] = dot2bf(wv[t].y, hv[t], a[1]);
            a[2] = dot2bf(wv[t].z, hv[t], a[2]);
            a[3] = dot2bf(wv[t].w, hv[t], a[3]);
        }
        *(vf4*)(&s_part[sub * 260 + j4]) = a;
        if (jg < 4) {                                   // tail cols 256..259
            float e = 0.f;
            #pragma unroll
            for (int t = 0; t < 8; ++t) {
                uint w = *(const uint*)(wfb + (size_t)(sub + 16 * t) * 520 + 512 + jg * 2);
                e = dot2bf(w, hv[t], e);
            }
            s_part[sub * 260 + 256 + jg] = e;
        }
    }
    __syncthreads();
    if (tid < 259) {
        float v = s_bf[tid];
        #pragma unroll
        for (int s = 0; s < 16; ++s) v += s_part[s * 260 + tid];
        s_o[tid] = tanhf(v);
    }
    __syncthreads();

    // ---- state update + direct outputs ----
    if (tid < 256) {
        float nh = s_in[195 + tid] + s_o[3 + tid];
        orow[3 + tid] = nh;
        s_h[tid] = nh;
        float v2 = __shfl_xor(nh, 1);
        if (!(tid & 1)) s_hb2[tid >> 1] = pack2(nh, v2);
    }
    if (tid == 256) orow[0] = s_in[0] + s_o[0];
    if (tid == 257) orow[1] = s_in[1] + s_o[1];
    if (tid == 258) orow[2] = s_in[2] + s_o[2];
    __syncthreads();

    // ---- c0 = relu(nh @ cw0 + cb0) ----
    {
        uint4 wv[8]; uint hv[8];
        #pragma unroll
        for (int t = 0; t < 8; ++t)
            wv[t] = *(const uint4*)(cw0b + (size_t)(sub + 16 * t) * 512 + jg * 8);
        #pragma unroll
        for (int t = 0; t < 8; ++t) hv[t] = s_hb2[sub + 16 * t];
        vf4 a = {0.f, 0.f, 0.f, 0.f};
        #pragma unroll
        for (int t = 0; t < 8; ++t) {
            a[0] = dot2bf(wv[t].x, hv[t], a[0]);
            a[1] = dot2bf(wv[t].y, hv[t], a[1]);
            a[2] = dot2bf(wv[t].z, hv[t], a[2]);
            a[3] = dot2bf(wv[t].w, hv[t], a[3]);
        }
        *(vf4*)(&s_part[sub * 256 + j4]) = a;
    }
    __syncthreads();
    if (tid < 256) {
        float v = s_cb0[tid];
        #pragma unroll
        for (int s = 0; s < 16; ++s) v += s_part[s * 256 + tid];
        v = fmaxf(v, 0.f);
        s_c[tid] = v;
        float v2 = __shfl_xor(v, 1);
        if (!(tid & 1)) s_cb2[tid >> 1] = pack2(v, v2);
    }
    __syncthreads();

    // ---- c1 = relu(c0 @ crw + crb + c0) ----
    {
        uint4 wv[8]; uint hv[8];
        #pragma unroll
        for (int t = 0; t < 8; ++t)
            wv[t] = *(const uint4*)(crwb + (size_t)(sub + 16 * t) * 512 + jg * 8);
        #pragma unroll
        for (int t = 0; t < 8; ++t) hv[t] = s_cb2[sub + 16 * t];
        vf4 a = {0.f, 0.f, 0.f, 0.f};
        #pragma unroll
        for (int t = 0; t < 8; ++t) {
            a[0] = dot2bf(wv[t].x, hv[t], a[0]);
            a[1] = dot2bf(wv[t].y, hv[t], a[1]);
            a[2] = dot2bf(wv[t].z, hv[t], a[2]);
            a[3] = dot2bf(wv[t].w, hv[t], a[3]);
        }
        *(vf4*)(&s_part[sub * 256 + j4]) = a;
    }
    __syncthreads();
    if (tid < 256) {
        float v = s_crb[tid] + s_c[tid];
        #pragma unroll
        for (int s = 0; s < 16; ++s) v += s_part[s * 256 + tid];
        v = fmaxf(v, 0.f);
        float v2 = __shfl_xor(v, 1);
        if (!(tid & 1)) s_cb2[tid >> 1] = pack2(v, v2);
    }
    __syncthreads();

    // ---- logits pass 1: cols 0..511 (8-way kp split) ----
    int jg8 = tid & 127, sub8 = tid >> 7;
    int c4 = jg8 * 4;
    {
        uint4 wv[16]; uint hv[16];
        #pragma unroll
        for (int t = 0; t < 16; ++t)
            wv[t] = *(const uint4*)(cw1b + (size_t)(sub8 + 8 * t) * 2000 + c4 * 2);
        #pragma unroll
        for (int t = 0; t < 16; ++t) hv[t] = s_cb2[sub8 + 8 * t];
        vf4 a = {0.f, 0.f, 0.f, 0.f};
        #pragma unroll
        for (int t = 0; t < 16; ++t) {
            a[0] = dot2bf(wv[t].x, hv[t], a[0]);
            a[1] = dot2bf(wv[t].y, hv[t], a[1]);
            a[2] = dot2bf(wv[t].z, hv[t], a[2]);
            a[3] = dot2bf(wv[t].w, hv[t], a[3]);
        }
        *(vf4*)(&s_part[sub8 * 512 + c4]) = a;
    }
    __syncthreads();
    if (tid < 512) {
        float v = s_cb1[tid];
        #pragma unroll
        for (int s = 0; s < 8; ++s) v += s_part[s * 512 + tid];
        s_lg[tid] = v;
    }
    __syncthreads();

    // ---- logits pass 2: cols 512..999 ----
    {
        vf4 a = {0.f, 0.f, 0.f, 0.f};
        if (jg8 < 122) {
            uint4 wv[16]; uint hv[16];
            #pragma unroll
            for (int t = 0; t < 16; ++t)
                wv[t] = *(const uint4*)(cw1b + (size_t)(sub8 + 8 * t) * 2000 + (512 + c4) * 2);
            #pragma unroll
            for (int t = 0; t < 16; ++t) hv[t] = s_cb2[sub8 + 8 * t];
            #pragma unroll
            for (int t = 0; t < 16; ++t) {
                a[0] = dot2bf(wv[t].x, hv[t], a[0]);
                a[1] = dot2bf(wv[t].y, hv[t], a[1]);
                a[2] = dot2bf(wv[t].z, hv[t], a[2]);
                a[3] = dot2bf(wv[t].w, hv[t], a[3]);
            }
        }
        *(vf4*)(&s_part[sub8 * 512 + c4]) = a;
    }
    __syncthreads();
    if (tid < 488) {
        float v = s_cb1[512 + tid];
        #pragma unroll
        for (int s = 0; s < 8; ++s) v += s_part[s * 512 + tid];
        s_lg[512 + tid] = v;
    }
    __syncthreads();

    // ---- softmax over 1000 ----
    float lgv = (tid < 1000) ? s_lg[tid] : -1e30f;
    int lane = tid & 63, wid = tid >> 6;
    float m = lgv;
    #pragma unroll
    for (int off = 1; off < 64; off <<= 1) m = fmaxf(m, __shfl_xor(m, off));
    if (lane == 0) s_red[wid] = m;
    __syncthreads();
    m = s_red[0];
    #pragma unroll
    for (int w = 1; w < 16; ++w) m = fmaxf(m, s_red[w]);

    float e = (tid < 1000) ? expf(lgv - m) : 0.f;
    float lsum = e;
    #pragma unroll
    for (int off = 1; off < 64; off <<= 1) lsum += __shfl_xor(lsum, off);
    if (lane == 0) s_red[16 + wid] = lsum;
    __syncthreads();
    float total = 0.f;
    #pragma unroll
    for (int w = 0; w < 16; ++w) total += s_red[16 + w];

    if (tid < 1000) orow[259 + tid] = e / total;
}

extern "C" void kernel_launch(void* const* d_in, const int* in_sizes, int n_in,
                              void* d_out, int out_size, void* d_ws, size_t ws_size,
                              hipStream_t stream) {
    const float* image  = (const float*)d_in[0];
    const float* loc    = (const float*)d_in[1];
    const float* scl    = (const float*)d_in[2];
    const float* hidden = (const float*)d_in[3];
    const float* w0  = (const float*)d_in[4];
    const float* b0  = (const float*)d_in[5];
    const float* rw  = (const float*)d_in[6];
    const float* rb  = (const float*)d_in[7];
    const float* wf  = (const float*)d_in[8];
    const float* bf  = (const float*)d_in[9];
    const float* cw0 = (const float*)d_in[10];
    const float* cb0 = (const float*)d_in[11];
    const float* crw = (const float*)d_in[12];
    const float* crb = (const float*)d_in[13];
    const float* cw1 = (const float*)d_in[14];
    const float* cb1 = (const float*)d_in[15];

    float* ws   = (float*)d_ws;
    float* pix  = ws;                          // 24576 floats
    ushort* bfa = (ushort*)(ws + 24576);       // 838656 ushorts (~1.68 MB)

    hipLaunchKernelGGL(interp_convert_kernel, dim3(384 + 512), dim3(256), 0, stream,
                       image, loc, scl, pix, w0, rw, wf, cw0, crw, cw1, bfa);
    hipLaunchKernelGGL(mlp_fused, dim3(BB), dim3(1024), 0, stream,
                       loc, scl, hidden, pix, bfa,
                       b0, rb, bf, cb0, crb, cb1, (float*)d_out);
}